// Round 6
// baseline (105.126 us; speedup 1.0000x reference)
//
#include <hip/hip_runtime.h>

// SIM hard search: per-column stream compaction of first K topic-matching
// values. L=2048, B=4096, K=256 nominal; derived at launch from sizes.
//
// Round 5 resubmit (round-5 bench failed on GPU acquisition, never ran).
//   Kernel A (mask build): thread = (32-row word w, column-PAIR c2). int2
//     loads -> 512B per wave-instruction, 32-deep register batch; writes
//     mask[w][c..c+1] as one uint2. ~5 us for the 32 MB topics scan.
//   Kernel C (scan+gather): thread = (w, c); W=64 prefix loop FULLY unrolled
//     (template) so all 64 L2-resident mask loads issue as one batch.
//     Zero-fills its KPT owned ranks where rank >= total (disjoint from
//     scatter targets -> no ordering needed), then gathers matched user_seq
//     values and scatters to ranks base.. while < K.
// No __syncthreads anywhere.

#define WORD_ROWS 32

// ---- Kernel A, vectorized (B even): 2 columns per thread via int2 ----
__global__ __launch_bounds__(256) void simhs_mask2_kernel(
    const int* __restrict__ topics,
    const int* __restrict__ tgt_topic,
    unsigned int* __restrict__ mask,   // [W][B]
    int L, int B, int W)
{
    const int halfB = B >> 1;
    const int tid = blockIdx.x * blockDim.x + threadIdx.x;
    if (tid >= W * halfB) return;
    const int c2 = tid % halfB;        // consecutive lanes -> consecutive pairs
    const int w  = tid / halfB;
    const int c  = c2 * 2;
    const int2 tt = *(const int2*)(tgt_topic + c);
    const int r0 = w * WORD_ROWS;
    const int* tp = topics + (size_t)r0 * B + c;

    unsigned int m0 = 0u, m1 = 0u;
    if (r0 + WORD_ROWS <= L) {
        int2 v[WORD_ROWS];             // statically indexed -> stays in VGPRs
        #pragma unroll
        for (int i = 0; i < WORD_ROWS; ++i)
            v[i] = *(const int2*)(tp + (size_t)i * B);
        #pragma unroll
        for (int i = 0; i < WORD_ROWS; ++i) {
            m0 |= (v[i].x == tt.x ? 1u : 0u) << i;
            m1 |= (v[i].y == tt.y ? 1u : 0u) << i;
        }
    } else {
        for (int i = 0; r0 + i < L; ++i) {
            int2 v = *(const int2*)(tp + (size_t)i * B);
            m0 |= (v.x == tt.x ? 1u : 0u) << i;
            m1 |= (v.y == tt.y ? 1u : 0u) << i;
        }
    }
    *(uint2*)(mask + (size_t)w * B + c) = make_uint2(m0, m1);
}

// ---- Kernel A, scalar fallback (B odd) ----
__global__ __launch_bounds__(256) void simhs_mask_kernel(
    const int* __restrict__ topics,
    const int* __restrict__ tgt_topic,
    unsigned int* __restrict__ mask,
    int L, int B, int W)
{
    const int tid = blockIdx.x * blockDim.x + threadIdx.x;
    if (tid >= W * B) return;
    const int c = tid % B;
    const int w = tid / B;
    const int tt = tgt_topic[c];
    const int r0 = w * WORD_ROWS;
    const int* tp = topics + (size_t)r0 * B + c;

    unsigned int m = 0u;
    for (int i = 0; r0 + i < L && i < WORD_ROWS; ++i)
        m |= (tp[(size_t)i * B] == tt ? 1u : 0u) << i;
    mask[tid] = m;
}

// ---- Kernel C: prefix + zero-fill + gather/scatter ----
template <int WT>
__global__ __launch_bounds__(256) void simhs_gather_kernel(
    const float* __restrict__ user_seq,
    const unsigned int* __restrict__ mask,   // [W][B]
    float* __restrict__ out,                 // [K][B]
    int B, int K, int KPT)
{
    const int tid = blockIdx.x * blockDim.x + threadIdx.x;
    if (tid >= WT * B) return;
    const int c = tid % B;
    const int w = tid / B;

    // Full-unroll prefix over this column's WT words: all loads batch-issue,
    // 1 MB array is L2-resident, each load lane-coalesced (256B/wave).
    unsigned int mm[WT];
    #pragma unroll
    for (int w2 = 0; w2 < WT; ++w2)
        mm[w2] = mask[(size_t)w2 * B + c];

    int base = 0, total = 0;
    unsigned int mym = 0u;
    #pragma unroll
    for (int w2 = 0; w2 < WT; ++w2) {
        if (w2 == w) { mym = mm[w2]; base = total; }
        total += __popc(mm[w2]);
    }

    // Zero-fill owned ranks no scatter will write (rank >= total).
    const int k0 = w * KPT;
    #pragma unroll
    for (int j = 0; j < 4; ++j) {
        int k = k0 + j;
        if (j < KPT && k < K && k >= total)
            out[(size_t)k * B + c] = 0.0f;
    }

    // Gather matched values, scatter to output ranks (disjoint from zeros).
    const float* us = user_seq + c;
    const int r0 = w * WORD_ROWS;
    while (mym) {
        if (base >= K) break;
        int lr = __ffs(mym) - 1;
        mym &= mym - 1;
        out[(size_t)base * B + c] = us[(size_t)(r0 + lr) * B];
        ++base;
    }
}

// Generic-W fallback (runtime loop, unroll 8)
__global__ __launch_bounds__(256) void simhs_gather_gen_kernel(
    const float* __restrict__ user_seq,
    const unsigned int* __restrict__ mask,
    float* __restrict__ out,
    int B, int K, int W, int KPT)
{
    const int tid = blockIdx.x * blockDim.x + threadIdx.x;
    if (tid >= W * B) return;
    const int c = tid % B;
    const int w = tid / B;

    unsigned int mym = 0u;
    int base = 0, total = 0;
    #pragma unroll 8
    for (int w2 = 0; w2 < W; ++w2) {
        unsigned int mm = mask[(size_t)w2 * B + c];
        if (w2 == w) { mym = mm; base = total; }
        total += __popc(mm);
    }
    const int k0 = w * KPT;
    for (int j = 0; j < KPT; ++j) {
        int k = k0 + j;
        if (k < K && k >= total)
            out[(size_t)k * B + c] = 0.0f;
    }
    const float* us = user_seq + c;
    const int r0 = w * WORD_ROWS;
    while (mym) {
        if (base >= K) break;
        int lr = __ffs(mym) - 1;
        mym &= mym - 1;
        out[(size_t)base * B + c] = us[(size_t)(r0 + lr) * B];
        ++base;
    }
}

extern "C" void kernel_launch(void* const* d_in, const int* in_sizes, int n_in,
                              void* d_out, int out_size, void* d_ws, size_t ws_size,
                              hipStream_t stream) {
    const float* user_seq = (const float*)d_in[0];
    // d_in[1] = target_item (unused by the reference computation)
    const int* topics = (const int*)d_in[2];
    const int* tgt    = (const int*)d_in[3];
    // d_in[4] = top_k scalar on device; recover K from out_size instead.

    const int B = in_sizes[1];                     // 4096
    const int L = in_sizes[0] / B;                 // 2048
    const int K = out_size / B;                    // 256
    const int W = (L + WORD_ROWS - 1) / WORD_ROWS; // 64
    const int KPT = (K + W - 1) / W;               // 4

    unsigned int* mask = (unsigned int*)d_ws;      // W*B*4 = 1 MB

    // Kernel A
    if ((B & 1) == 0) {
        const int nthr = W * (B >> 1);             // 131072
        simhs_mask2_kernel<<<(nthr + 255) / 256, 256, 0, stream>>>(
            topics, tgt, mask, L, B, W);
    } else {
        const int nthr = W * B;
        simhs_mask_kernel<<<(nthr + 255) / 256, 256, 0, stream>>>(
            topics, tgt, mask, L, B, W);
    }

    // Kernel C
    const int nthr = W * B;                        // 262144
    const int grid = (nthr + 255) / 256;           // 1024
    if (W == 64 && KPT <= 4)
        simhs_gather_kernel<64><<<grid, 256, 0, stream>>>(
            user_seq, mask, (float*)d_out, B, K, KPT);
    else
        simhs_gather_gen_kernel<<<grid, 256, 0, stream>>>(
            user_seq, mask, (float*)d_out, B, K, W, KPT);
}